// Round 3
// baseline (483.155 us; speedup 1.0000x reference)
//
#include <hip/hip_runtime.h>

// ---- problem constants ----
#define T_SEQ 2048
#define NB    2
#define NHEAD 16
#define NKV   4
#define HD    128
#define CDIM  2048
#define QKV_W 3072            // 2048 q + 512 k (+ 512 v, routed to Vt instead)
#define MROWS 4096            // B*T

// 1/sqrt(128) * log2(e), folded into q at RoPE time so attention uses exp2 directly
#define QSCALE 0.12752648137154393f

typedef unsigned int  uint;
typedef unsigned short ushort;

typedef __attribute__((ext_vector_type(8))) __bf16 bf16x8;
typedef __attribute__((ext_vector_type(4))) float  floatx4;

#if __has_builtin(__builtin_amdgcn_exp2f)
#define EXP2F(x) __builtin_amdgcn_exp2f(x)
#else
#define EXP2F(x) exp2f(x)
#endif

__device__ __forceinline__ uint bf16rne(float f) {
  uint u = __float_as_uint(f);
  u += 0x7fffu + ((u >> 16) & 1u);
  return u >> 16;
}
__device__ __forceinline__ float bflo(uint w) { return __uint_as_float(w << 16); }
__device__ __forceinline__ float bfhi(uint w) { return __uint_as_float(w & 0xffff0000u); }

// ---- fp32 -> bf16 cast, 2 elems/thread ----
__global__ void cast_f32_bf16x2(const float* __restrict__ in, uint* __restrict__ out, int n2) {
  int i = blockIdx.x * 256 + threadIdx.x;
  if (i < n2) {
    float2 v = ((const float2*)in)[i];
    out[i] = bf16rne(v.x) | (bf16rne(v.y) << 16);
  }
}

// ---- GEMM C[M,N] = A[M,K] * Bt[N,K]^T  (bf16 in, OutT out) ----
// Columns >= vcol0 are written TRANSPOSED into vt as [(b*512 + (col-vcol0))][T] bf16.
__device__ __forceinline__ void store_elem(ushort* C, size_t idx, float v) { C[idx] = (ushort)bf16rne(v); }
__device__ __forceinline__ void store_elem(float*  C, size_t idx, float v) { C[idx] = v; }

template <typename OutT>
__global__ __launch_bounds__(256) void gemm_bt(const ushort* __restrict__ A,
                                               const ushort* __restrict__ Bt,
                                               OutT* __restrict__ C,
                                               int M, int N, int K,
                                               int vcol0, ushort* __restrict__ vt) {
  __shared__ ushort sA[128 * 32];
  __shared__ ushort sB[128 * 32];
  const int tid  = threadIdx.x;
  const int wave = tid >> 6, lane = tid & 63;
  const int quad = lane >> 4, l16 = lane & 15;
  const int wy = wave >> 1, wx = wave & 1;
  const int mBase = blockIdx.y << 7;
  const int nBase = blockIdx.x << 7;

  floatx4 acc[4][4];
#pragma unroll
  for (int i = 0; i < 4; ++i)
#pragma unroll
    for (int j = 0; j < 4; ++j)
#pragma unroll
      for (int r = 0; r < 4; ++r) acc[i][j][r] = 0.f;

  const int e0 = ((wave << 1) + 0) * 512 + lane * 8;
  const int e1 = ((wave << 1) + 1) * 512 + lane * 8;
  const int r0 = e0 >> 5, c0 = e0 & 31;
  const int r1 = e1 >> 5, c1 = e1 & 31;
  const ushort* Ag0 = A  + (size_t)(mBase + r0) * K + c0;
  const ushort* Ag1 = A  + (size_t)(mBase + r1) * K + c1;
  const ushort* Bg0 = Bt + (size_t)(nBase + r0) * K + c0;
  const ushort* Bg1 = Bt + (size_t)(nBase + r1) * K + c1;
  ushort* sA0 = &sA[((wave << 1) + 0) * 512];
  ushort* sA1 = &sA[((wave << 1) + 1) * 512];
  ushort* sB0 = &sB[((wave << 1) + 0) * 512];
  ushort* sB1 = &sB[((wave << 1) + 1) * 512];

  for (int k0 = 0; k0 < K; k0 += 32) {
    __builtin_amdgcn_global_load_lds((const __attribute__((address_space(1))) void*)(Ag0 + k0),
                                     (__attribute__((address_space(3))) void*)sA0, 16, 0, 0);
    __builtin_amdgcn_global_load_lds((const __attribute__((address_space(1))) void*)(Ag1 + k0),
                                     (__attribute__((address_space(3))) void*)sA1, 16, 0, 0);
    __builtin_amdgcn_global_load_lds((const __attribute__((address_space(1))) void*)(Bg0 + k0),
                                     (__attribute__((address_space(3))) void*)sB0, 16, 0, 0);
    __builtin_amdgcn_global_load_lds((const __attribute__((address_space(1))) void*)(Bg1 + k0),
                                     (__attribute__((address_space(3))) void*)sB1, 16, 0, 0);
    __syncthreads();
    bf16x8 af[4], bfr[4];
#pragma unroll
    for (int i = 0; i < 4; ++i) {
      af[i]  = *(const bf16x8*)&sA[((wy << 6) + (i << 4) + l16) * 32 + (quad << 3)];
      bfr[i] = *(const bf16x8*)&sB[((wx << 6) + (i << 4) + l16) * 32 + (quad << 3)];
    }
#pragma unroll
    for (int i = 0; i < 4; ++i)
#pragma unroll
      for (int j = 0; j < 4; ++j)
        acc[i][j] = __builtin_amdgcn_mfma_f32_16x16x32_bf16(af[i], bfr[j], acc[i][j], 0, 0, 0);
    __syncthreads();
  }

#pragma unroll
  for (int i = 0; i < 4; ++i) {
    const int rowb = mBase + (wy << 6) + (i << 4) + (quad << 2);
#pragma unroll
    for (int j = 0; j < 4; ++j) {
      const int colb = nBase + (wx << 6) + (j << 4);
      const int col  = colb + l16;
      if (colb < vcol0) {
#pragma unroll
        for (int r = 0; r < 4; ++r)
          store_elem(C, (size_t)(rowb + r) * N + col, acc[i][j][r]);
      } else {
        const int vcol = col - vcol0;
        const int bb = rowb >> 11;
        const int t  = rowb & 2047;
        uint2 pw;
        pw.x = bf16rne(acc[i][j][0]) | (bf16rne(acc[i][j][1]) << 16);
        pw.y = bf16rne(acc[i][j][2]) | (bf16rne(acc[i][j][3]) << 16);
        *(uint2*)(vt + (((size_t)(bb << 9) + vcol) << 11) + t) = pw;
      }
    }
  }
}

// ---- RoPE in-place on qkv; q additionally scaled by QSCALE ----
__global__ void rope_kernel(ushort* __restrict__ qkv, const float* __restrict__ fc,
                            const float* __restrict__ fs) {
  int idx  = blockIdx.x * 256 + threadIdx.x;   // exactly B*T*20*64 threads
  int d2   = idx & 63;
  int rest = idx >> 6;
  int hh   = rest % 20;
  int bt   = rest / 20;
  int t    = bt & (T_SEQ - 1);
  float c = fc[(t << 6) + d2];
  float s = fs[(t << 6) + d2];
  int col = (hh < 16) ? ((hh << 7) + (d2 << 1)) : (2048 + ((hh - 16) << 7) + (d2 << 1));
  float m = (hh < 16) ? QSCALE : 1.0f;
  uint* p = (uint*)(qkv + (size_t)bt * QKV_W + col);
  uint w = *p;
  float e = bflo(w), o = bfhi(w);
  float oe = (e * c - o * s) * m;
  float oo = (e * s + o * c) * m;
  *p = bf16rne(oe) | (bf16rne(oo) << 16);
}

// ---- MFMA flash attention, Q-tile 64, key tile 64, 4 waves, 512 blocks ----
// Blocks paired over Q-tiles {x, 31-x}: exactly 33 key-iters/block, 2 blocks/CU.
// QK: wave (w_hi: s-block 32, w_lo: t-block 32) computes S^T = mfma(Kfrag, Qfrag).
// PV: wave (w_lo: t-block 32, w_hi: d-block 64): O += mfma(Pfrag, Vtfrag),
//     l += mfma(Pfrag, ones) -> same C-layout as O.
__global__ __launch_bounds__(256, 2) void attn_mfma(const ushort* __restrict__ qkv,
                                                    const ushort* __restrict__ vtg,
                                                    ushort* __restrict__ y) {
  __shared__ ushort smem[20992];          // 41984 B
  ushort* sK  = smem;                     // [64][128] bf16, XOR-swizzled chunks (16 KB)
  ushort* sVt = smem + 8192;              // [128][64] bf16, XOR-swizzled chunks (16 KB)
  ushort* sP  = smem + 16384;             // [64][72] bf16 (9 KB)
  ushort* sO  = smem;                     // epilogue overlay [64][136] (17.4 KB)

  const int tid  = threadIdx.x;
  const int wave = tid >> 6, lane = tid & 63;
  const int quad = lane >> 4, l16 = lane & 15;
  const int w_hi = wave >> 1, w_lo = wave & 1;
  const int h = blockIdx.y, b = blockIdx.z, kh = h >> 2;
  const size_t bT = (size_t)b * T_SEQ;

  union { uint4 u; bf16x8 v; } ones_u;
  ones_u.u = make_uint4(0x3F803F80u, 0x3F803F80u, 0x3F803F80u, 0x3F803F80u);
  const bf16x8 onesf = ones_u.v;

  for (int half = 0; half < 2; ++half) {
    const int xt = half ? (31 - (int)blockIdx.x) : (int)blockIdx.x;
    const int t0 = xt << 6;

    // Q fragments for this wave's QK t-block (t-block = w_lo*32, 2 tiles of 16)
    bf16x8 qf[2][4];
    {
      const int tq = t0 + (w_lo << 5);
#pragma unroll
      for (int tt = 0; tt < 2; ++tt)
#pragma unroll
        for (int kk = 0; kk < 4; ++kk)
          qf[tt][kk] = *(const bf16x8*)(qkv + (bT + tq + tt * 16 + l16) * QKV_W +
                                        h * HD + kk * 32 + quad * 8);
    }

    floatx4 oacc[2][4];
    floatx4 lacc[2];
#pragma unroll
    for (int tt = 0; tt < 2; ++tt) {
#pragma unroll
      for (int r = 0; r < 4; ++r) lacc[tt][r] = 0.f;
#pragma unroll
      for (int dt = 0; dt < 4; ++dt)
#pragma unroll
        for (int r = 0; r < 4; ++r) oacc[tt][dt][r] = 0.f;
    }

    const int nch = (t0 >> 6) + 1;
    uint4 kreg[4], vreg[4];
    // prefetch stage regs for ch = 0
    {
#pragma unroll
      for (int it = 0; it < 4; ++it) {
        int idx = it * 256 + tid;
        int r = idx >> 4, c8 = idx & 15;
        kreg[it] = *(const uint4*)(qkv + (bT + r) * QKV_W + 2048 + kh * HD + c8 * 8);
      }
#pragma unroll
      for (int it = 0; it < 4; ++it) {
        int idx = it * 256 + tid;
        int d = idx >> 3, sc = idx & 7;
        vreg[it] = *(const uint4*)(vtg + (((size_t)(b << 9) + (kh << 7) + d) << 11) + sc * 8);
      }
    }

    for (int ch = 0; ch < nch; ++ch) {
      const int s0 = ch << 6;
      __syncthreads();   // previous tile fully consumed (and sO stores done)
#pragma unroll
      for (int it = 0; it < 4; ++it) {
        int idx = it * 256 + tid;
        int r = idx >> 4, c8 = idx & 15;
        *(uint4*)(sK + r * 128 + ((c8 ^ (r & 7)) << 3)) = kreg[it];
      }
#pragma unroll
      for (int it = 0; it < 4; ++it) {
        int idx = it * 256 + tid;
        int d = idx >> 3, sc = idx & 7;
        *(uint4*)(sVt + d * 64 + ((sc ^ (d & 7)) << 3)) = vreg[it];
      }
      __syncthreads();
      // prefetch next tile while computing on this one
      if (ch + 1 < nch) {
        const int sn = s0 + 64;
#pragma unroll
        for (int it = 0; it < 4; ++it) {
          int idx = it * 256 + tid;
          int r = idx >> 4, c8 = idx & 15;
          kreg[it] = *(const uint4*)(qkv + (bT + sn + r) * QKV_W + 2048 + kh * HD + c8 * 8);
        }
#pragma unroll
        for (int it = 0; it < 4; ++it) {
          int idx = it * 256 + tid;
          int d = idx >> 3, sc = idx & 7;
          vreg[it] = *(const uint4*)(vtg + (((size_t)(b << 9) + (kh << 7) + d) << 11) + sn + sc * 8);
        }
      }

      const int sblk = w_hi << 5, tblk = w_lo << 5;
      floatx4 accS[2][2];
#pragma unroll
      for (int st = 0; st < 2; ++st)
#pragma unroll
        for (int tt = 0; tt < 2; ++tt)
#pragma unroll
          for (int r = 0; r < 4; ++r) accS[st][tt][r] = 0.f;

#pragma unroll
      for (int kk = 0; kk < 4; ++kk) {
        bf16x8 kf0 = *(const bf16x8*)(sK + (sblk + l16) * 128 +
                                      ((((kk << 2) + quad) ^ (l16 & 7)) << 3));
        bf16x8 kf1 = *(const bf16x8*)(sK + (sblk + 16 + l16) * 128 +
                                      ((((kk << 2) + quad) ^ (l16 & 7)) << 3));
#pragma unroll
        for (int tt = 0; tt < 2; ++tt)
          accS[0][tt] = __builtin_amdgcn_mfma_f32_16x16x32_bf16(kf0, qf[tt][kk], accS[0][tt], 0, 0, 0);
#pragma unroll
        for (int tt = 0; tt < 2; ++tt)
          accS[1][tt] = __builtin_amdgcn_mfma_f32_16x16x32_bf16(kf1, qf[tt][kk], accS[1][tt], 0, 0, 0);
      }

      const bool diag = (s0 + sblk + 31) > (t0 + tblk);
#pragma unroll
      for (int st = 0; st < 2; ++st)
#pragma unroll
        for (int tt = 0; tt < 2; ++tt) {
          float p[4];
          if (diag) {
            const int sg = s0 + sblk + st * 16 + quad * 4;
            const int tg = t0 + tblk + tt * 16 + l16;
#pragma unroll
            for (int r = 0; r < 4; ++r)
              p[r] = (sg + r <= tg) ? EXP2F(accS[st][tt][r]) : 0.f;
          } else {
#pragma unroll
            for (int r = 0; r < 4; ++r) p[r] = EXP2F(accS[st][tt][r]);
          }
          uint2 pw;   // truncating bf16 pack (bias cancels in normalization)
          pw.x = (__float_as_uint(p[0]) >> 16) | (__float_as_uint(p[1]) & 0xFFFF0000u);
          pw.y = (__float_as_uint(p[2]) >> 16) | (__float_as_uint(p[3]) & 0xFFFF0000u);
          *(uint2*)(sP + (tblk + tt * 16 + l16) * 72 + sblk + st * 16 + quad * 4) = pw;
        }
      __syncthreads();   // P visible to all waves

      // PV: O[t][d] += P * Vt^T ; l[t] += P * 1   (t-block = w_lo*32, d-block = w_hi*64)
#pragma unroll
      for (int ss = 0; ss < 2; ++ss) {
        bf16x8 pf[2];
#pragma unroll
        for (int tt = 0; tt < 2; ++tt)
          pf[tt] = *(const bf16x8*)(sP + ((w_lo << 5) + tt * 16 + l16) * 72 +
                                    (ss << 5) + (quad << 3));
#pragma unroll
        for (int tt = 0; tt < 2; ++tt)
          lacc[tt] = __builtin_amdgcn_mfma_f32_16x16x32_bf16(pf[tt], onesf, lacc[tt], 0, 0, 0);
#pragma unroll
        for (int dt = 0; dt < 4; ++dt) {
          bf16x8 vf = *(const bf16x8*)(sVt + ((w_hi << 6) + dt * 16 + l16) * 64 +
                                       ((((ss << 2) + quad) ^ (l16 & 7)) << 3));
#pragma unroll
          for (int tt = 0; tt < 2; ++tt)
            oacc[tt][dt] = __builtin_amdgcn_mfma_f32_16x16x32_bf16(pf[tt], vf, oacc[tt][dt], 0, 0, 0);
        }
      }
    }

    // epilogue: normalize, transpose O through LDS, coalesced store
    __syncthreads();   // all PV reads of sK/sVt/sP done
#pragma unroll
    for (int tt = 0; tt < 2; ++tt) {
      floatx4 li;
#pragma unroll
      for (int r = 0; r < 4; ++r) li[r] = 1.0f / lacc[tt][r];
#pragma unroll
      for (int dt = 0; dt < 4; ++dt)
#pragma unroll
        for (int r = 0; r < 4; ++r) {
          float v = oacc[tt][dt][r] * li[r];
          sO[((w_lo << 5) + tt * 16 + quad * 4 + r) * 136 + (w_hi << 6) + dt * 16 + l16] =
              (ushort)bf16rne(v);
        }
    }
    __syncthreads();
#pragma unroll
    for (int it = 0; it < 4; ++it) {
      int idx = it * 256 + tid;
      int rr = idx >> 4, c8 = idx & 15;
      *(uint4*)(y + (bT + t0 + rr) * CDIM + h * HD + c8 * 8) =
          *(const uint4*)(sO + rr * 136 + c8 * 8);
    }
    // top-of-next-half barrier (inside ch loop) protects sO before restaging
  }
}

extern "C" void kernel_launch(void* const* d_in, const int* in_sizes, int n_in,
                              void* d_out, int out_size, void* d_ws, size_t ws_size,
                              hipStream_t stream) {
  const float* x    = (const float*)d_in[0];
  const float* fcos = (const float*)d_in[1];
  const float* fsin = (const float*)d_in[2];
  const float* wq   = (const float*)d_in[3];
  const float* wk   = (const float*)d_in[4];
  const float* wv   = (const float*)d_in[5];
  const float* wo   = (const float*)d_in[6];
  float* out = (float*)d_out;

  // workspace carve (bf16 elems); yb aliases xb (xb dead after gemm1)
  ushort* ws    = (ushort*)d_ws;
  ushort* xb    = ws;                          // 4096*2048 = 8,388,608
  ushort* yb    = ws;                          // alias of xb
  ushort* wqkvb = ws    + 8388608;             // 3072*2048 = 6,291,456
  ushort* wob   = wqkvb + 6291456;             // 2048*2048 = 4,194,304
  ushort* qkv   = wob   + 4194304;             // 4096*3072 = 12,582,912 (v cols unused)
  ushort* vtg   = qkv   + 12582912;            // 2*512*2048 = 2,097,152

  // 1) fp32 -> bf16 casts; wq/wk/wv concatenated row-wise into Wqkv (3072 x 2048)
  cast_f32_bf16x2<<<16384, 256, 0, stream>>>(x,  (uint*)xb,    4194304);
  cast_f32_bf16x2<<< 8192, 256, 0, stream>>>(wq, (uint*)wqkvb, 2097152);
  cast_f32_bf16x2<<< 2048, 256, 0, stream>>>(wk, (uint*)(wqkvb + 4194304), 524288);
  cast_f32_bf16x2<<< 2048, 256, 0, stream>>>(wv, (uint*)(wqkvb + 5242880), 524288);
  cast_f32_bf16x2<<< 8192, 256, 0, stream>>>(wo, (uint*)wob,   2097152);

  // 2) qkv = xb @ Wqkv^T ; V columns (>=2560) written transposed into vtg
  gemm_bt<ushort><<<dim3(QKV_W / 128, MROWS / 128), 256, 0, stream>>>(
      xb, wqkvb, qkv, MROWS, QKV_W, CDIM, 2560, vtg);

  // 3) RoPE in place on q (scaled by QSCALE) and k
  rope_kernel<<<20480, 256, 0, stream>>>(qkv, fcos, fsin);

  // 4) MFMA causal GQA attention -> yb (bf16), Q-tile 64, paired {x, 31-x}
  attn_mfma<<<dim3(16, NHEAD, NB), 256, 0, stream>>>(qkv, vtg, yb);

  // 5) out = yb @ wo^T (fp32 out)
  gemm_bt<float><<<dim3(CDIM / 128, MROWS / 128), 256, 0, stream>>>(
      yb, wob, out, MROWS, CDIM, CDIM, 1 << 30, nullptr);
}

// Round 4
// 377.828 us; speedup vs baseline: 1.2788x; 1.2788x over previous
//
#include <hip/hip_runtime.h>

// ---- problem constants ----
#define T_SEQ 2048
#define NB    2
#define NHEAD 16
#define NKV   4
#define HD    128
#define CDIM  2048
#define QKV_W 3072            // 2048 q + 512 k (+ 512 v, routed to Vt instead)
#define MROWS 4096            // B*T

// 1/sqrt(128) * log2(e), folded into q at RoPE time so attention uses exp2 directly
#define QSCALE 0.12752648137154393f

typedef unsigned int  uint;
typedef unsigned short ushort;

typedef __attribute__((ext_vector_type(8))) __bf16 bf16x8;
typedef __attribute__((ext_vector_type(4))) float  floatx4;

#if __has_builtin(__builtin_amdgcn_exp2f)
#define EXP2F(x) __builtin_amdgcn_exp2f(x)
#else
#define EXP2F(x) exp2f(x)
#endif

__device__ __forceinline__ uint bf16rne(float f) {
  uint u = __float_as_uint(f);
  u += 0x7fffu + ((u >> 16) & 1u);
  return u >> 16;
}
__device__ __forceinline__ float bflo(uint w) { return __uint_as_float(w << 16); }
__device__ __forceinline__ float bfhi(uint w) { return __uint_as_float(w & 0xffff0000u); }

// ---- fp32 -> bf16 cast, 2 elems/thread ----
__global__ void cast_f32_bf16x2(const float* __restrict__ in, uint* __restrict__ out, int n2) {
  int i = blockIdx.x * 256 + threadIdx.x;
  if (i < n2) {
    float2 v = ((const float2*)in)[i];
    out[i] = bf16rne(v.x) | (bf16rne(v.y) << 16);
  }
}

// ---- GEMM C[M,N] = A[M,K] * Bt[N,K]^T  (bf16 in, OutT out) ----
// Columns >= vcol0 are written TRANSPOSED into vt as [(b*512 + (col-vcol0))][T] bf16.
__device__ __forceinline__ void store_elem(ushort* C, size_t idx, float v) { C[idx] = (ushort)bf16rne(v); }
__device__ __forceinline__ void store_elem(float*  C, size_t idx, float v) { C[idx] = v; }

template <typename OutT>
__global__ __launch_bounds__(256) void gemm_bt(const ushort* __restrict__ A,
                                               const ushort* __restrict__ Bt,
                                               OutT* __restrict__ C,
                                               int M, int N, int K,
                                               int vcol0, ushort* __restrict__ vt) {
  __shared__ ushort sA[128 * 32];
  __shared__ ushort sB[128 * 32];
  const int tid  = threadIdx.x;
  const int wave = tid >> 6, lane = tid & 63;
  const int quad = lane >> 4, l16 = lane & 15;
  const int wy = wave >> 1, wx = wave & 1;
  const int mBase = blockIdx.y << 7;
  const int nBase = blockIdx.x << 7;

  floatx4 acc[4][4];
#pragma unroll
  for (int i = 0; i < 4; ++i)
#pragma unroll
    for (int j = 0; j < 4; ++j)
#pragma unroll
      for (int r = 0; r < 4; ++r) acc[i][j][r] = 0.f;

  const int e0 = ((wave << 1) + 0) * 512 + lane * 8;
  const int e1 = ((wave << 1) + 1) * 512 + lane * 8;
  const int r0 = e0 >> 5, c0 = e0 & 31;
  const int r1 = e1 >> 5, c1 = e1 & 31;
  const ushort* Ag0 = A  + (size_t)(mBase + r0) * K + c0;
  const ushort* Ag1 = A  + (size_t)(mBase + r1) * K + c1;
  const ushort* Bg0 = Bt + (size_t)(nBase + r0) * K + c0;
  const ushort* Bg1 = Bt + (size_t)(nBase + r1) * K + c1;
  ushort* sA0 = &sA[((wave << 1) + 0) * 512];
  ushort* sA1 = &sA[((wave << 1) + 1) * 512];
  ushort* sB0 = &sB[((wave << 1) + 0) * 512];
  ushort* sB1 = &sB[((wave << 1) + 1) * 512];

  for (int k0 = 0; k0 < K; k0 += 32) {
    __builtin_amdgcn_global_load_lds((const __attribute__((address_space(1))) void*)(Ag0 + k0),
                                     (__attribute__((address_space(3))) void*)sA0, 16, 0, 0);
    __builtin_amdgcn_global_load_lds((const __attribute__((address_space(1))) void*)(Ag1 + k0),
                                     (__attribute__((address_space(3))) void*)sA1, 16, 0, 0);
    __builtin_amdgcn_global_load_lds((const __attribute__((address_space(1))) void*)(Bg0 + k0),
                                     (__attribute__((address_space(3))) void*)sB0, 16, 0, 0);
    __builtin_amdgcn_global_load_lds((const __attribute__((address_space(1))) void*)(Bg1 + k0),
                                     (__attribute__((address_space(3))) void*)sB1, 16, 0, 0);
    __syncthreads();
    bf16x8 af[4], bfr[4];
#pragma unroll
    for (int i = 0; i < 4; ++i) {
      af[i]  = *(const bf16x8*)&sA[((wy << 6) + (i << 4) + l16) * 32 + (quad << 3)];
      bfr[i] = *(const bf16x8*)&sB[((wx << 6) + (i << 4) + l16) * 32 + (quad << 3)];
    }
#pragma unroll
    for (int i = 0; i < 4; ++i)
#pragma unroll
      for (int j = 0; j < 4; ++j)
        acc[i][j] = __builtin_amdgcn_mfma_f32_16x16x32_bf16(af[i], bfr[j], acc[i][j], 0, 0, 0);
    __syncthreads();
  }

#pragma unroll
  for (int i = 0; i < 4; ++i) {
    const int rowb = mBase + (wy << 6) + (i << 4) + (quad << 2);
#pragma unroll
    for (int j = 0; j < 4; ++j) {
      const int colb = nBase + (wx << 6) + (j << 4);
      const int col  = colb + l16;
      if (colb < vcol0) {
#pragma unroll
        for (int r = 0; r < 4; ++r)
          store_elem(C, (size_t)(rowb + r) * N + col, acc[i][j][r]);
      } else {
        const int vcol = col - vcol0;
        const int bb = rowb >> 11;
        const int t  = rowb & 2047;
        uint2 pw;
        pw.x = bf16rne(acc[i][j][0]) | (bf16rne(acc[i][j][1]) << 16);
        pw.y = bf16rne(acc[i][j][2]) | (bf16rne(acc[i][j][3]) << 16);
        *(uint2*)(vt + (((size_t)(bb << 9) + vcol) << 11) + t) = pw;
      }
    }
  }
}

// ---- RoPE in-place on qkv; q additionally scaled by QSCALE ----
__global__ void rope_kernel(ushort* __restrict__ qkv, const float* __restrict__ fc,
                            const float* __restrict__ fs) {
  int idx  = blockIdx.x * 256 + threadIdx.x;   // exactly B*T*20*64 threads
  int d2   = idx & 63;
  int rest = idx >> 6;
  int hh   = rest % 20;
  int bt   = rest / 20;
  int t    = bt & (T_SEQ - 1);
  float c = fc[(t << 6) + d2];
  float s = fs[(t << 6) + d2];
  int col = (hh < 16) ? ((hh << 7) + (d2 << 1)) : (2048 + ((hh - 16) << 7) + (d2 << 1));
  float m = (hh < 16) ? QSCALE : 1.0f;
  uint* p = (uint*)(qkv + (size_t)bt * QKV_W + col);
  uint w = *p;
  float e = bflo(w), o = bfhi(w);
  float oe = (e * c - o * s) * m;
  float oo = (e * s + o * c) * m;
  *p = bf16rne(oe) | (bf16rne(oo) << 16);
}

// ---- MFMA flash attention: Q-tile 128, key tile 64, EIGHT waves (512 thr) ----
// Grid 256 blocks (1/CU), blocks paired over Q-tiles {x, 15-x}: 34 iters each.
// QK: wave split (w_s = wave&1 -> s-block 32, w_t = wave>>1 -> t-block 32):
//     S^T = mfma(Kfrag, Qfrag).
// PV: same split re-used (w_t -> t-block 32, w_s -> d-block 64):
//     O += mfma(Pfrag, Vtfrag), l += mfma(Pfrag, ones) -> same C-layout as O.
__global__ __launch_bounds__(512, 2) void attn_mfma(const ushort* __restrict__ qkv,
                                                    const ushort* __restrict__ vtg,
                                                    ushort* __restrict__ y) {
  __shared__ ushort smem[25600];          // 51200 B
  ushort* sK  = smem;                     // [64][128] bf16, XOR-swizzled chunks (16 KB)
  ushort* sVt = smem + 8192;              // [128][64] bf16, XOR-swizzled chunks (16 KB)
  ushort* sP  = smem + 16384;             // [128][72] bf16 (18 KB)
  ushort* sO  = smem;                     // epilogue overlay [128][136] (34.8 KB)

  const int tid  = threadIdx.x;
  const int wave = tid >> 6, lane = tid & 63;
  const int quad = lane >> 4, l16 = lane & 15;
  const int w_s = wave & 1;               // QK s-block / PV d-block
  const int w_t = wave >> 1;              // t-block (0..3), same in QK and PV
  const int h = blockIdx.y, b = blockIdx.z, kh = h >> 2;
  const size_t bT = (size_t)b * T_SEQ;

  union { uint4 u; bf16x8 v; } ones_u;
  ones_u.u = make_uint4(0x3F803F80u, 0x3F803F80u, 0x3F803F80u, 0x3F803F80u);
  const bf16x8 onesf = ones_u.v;

  for (int half = 0; half < 2; ++half) {
    const int xt = half ? (15 - (int)blockIdx.x) : (int)blockIdx.x;
    const int t0 = xt << 7;
    const int sblk = w_s << 5, tblk = w_t << 5;

    // Q fragments for this wave's t-block (32 rows = 2 MFMA tiles)
    bf16x8 qf[2][4];
#pragma unroll
    for (int tt = 0; tt < 2; ++tt)
#pragma unroll
      for (int kk = 0; kk < 4; ++kk)
        qf[tt][kk] = *(const bf16x8*)(qkv + (bT + t0 + tblk + tt * 16 + l16) * QKV_W +
                                      h * HD + kk * 32 + quad * 8);

    floatx4 oacc[2][4];
    floatx4 lacc[2];
#pragma unroll
    for (int tt = 0; tt < 2; ++tt) {
#pragma unroll
      for (int r = 0; r < 4; ++r) lacc[tt][r] = 0.f;
#pragma unroll
      for (int dt = 0; dt < 4; ++dt)
#pragma unroll
        for (int r = 0; r < 4; ++r) oacc[tt][dt][r] = 0.f;
    }

    const int nch = (t0 >> 6) + 2;
    uint4 kreg[2], vreg[2];
    // prefetch stage regs for ch = 0
#pragma unroll
    for (int it = 0; it < 2; ++it) {
      int idx = it * 512 + tid;                 // 0..1023
      int r = idx >> 4, c8 = idx & 15;
      kreg[it] = *(const uint4*)(qkv + (bT + r) * QKV_W + 2048 + kh * HD + c8 * 8);
    }
#pragma unroll
    for (int it = 0; it < 2; ++it) {
      int idx = it * 512 + tid;
      int d = idx >> 3, sc = idx & 7;
      vreg[it] = *(const uint4*)(vtg + (((size_t)(b << 9) + (kh << 7) + d) << 11) + sc * 8);
    }

    for (int ch = 0; ch < nch; ++ch) {
      const int s0 = ch << 6;
      __syncthreads();   // previous tile fully consumed (and sO stores done)
#pragma unroll
      for (int it = 0; it < 2; ++it) {
        int idx = it * 512 + tid;
        int r = idx >> 4, c8 = idx & 15;
        *(uint4*)(sK + r * 128 + ((c8 ^ (r & 7)) << 3)) = kreg[it];
      }
#pragma unroll
      for (int it = 0; it < 2; ++it) {
        int idx = it * 512 + tid;
        int d = idx >> 3, sc = idx & 7;
        *(uint4*)(sVt + d * 64 + ((sc ^ (d & 7)) << 3)) = vreg[it];
      }
      __syncthreads();
      // prefetch next tile while computing on this one
      if (ch + 1 < nch) {
        const int sn = s0 + 64;
#pragma unroll
        for (int it = 0; it < 2; ++it) {
          int idx = it * 512 + tid;
          int r = idx >> 4, c8 = idx & 15;
          kreg[it] = *(const uint4*)(qkv + (bT + sn + r) * QKV_W + 2048 + kh * HD + c8 * 8);
        }
#pragma unroll
        for (int it = 0; it < 2; ++it) {
          int idx = it * 512 + tid;
          int d = idx >> 3, sc = idx & 7;
          vreg[it] = *(const uint4*)(vtg + (((size_t)(b << 9) + (kh << 7) + d) << 11) + sn + sc * 8);
        }
      }

      // QK: this wave's s-block (32) x t-block (32)
      const bool fullmask = (s0 + sblk) > (t0 + tblk + 31);
      floatx4 accS[2][2];
#pragma unroll
      for (int st = 0; st < 2; ++st)
#pragma unroll
        for (int tt = 0; tt < 2; ++tt)
#pragma unroll
          for (int r = 0; r < 4; ++r) accS[st][tt][r] = 0.f;

      if (!fullmask) {
#pragma unroll
        for (int kk = 0; kk < 4; ++kk) {
          bf16x8 kf0 = *(const bf16x8*)(sK + (sblk + l16) * 128 +
                                        ((((kk << 2) + quad) ^ (l16 & 7)) << 3));
          bf16x8 kf1 = *(const bf16x8*)(sK + (sblk + 16 + l16) * 128 +
                                        ((((kk << 2) + quad) ^ (l16 & 7)) << 3));
#pragma unroll
          for (int tt = 0; tt < 2; ++tt)
            accS[0][tt] = __builtin_amdgcn_mfma_f32_16x16x32_bf16(kf0, qf[tt][kk], accS[0][tt], 0, 0, 0);
#pragma unroll
          for (int tt = 0; tt < 2; ++tt)
            accS[1][tt] = __builtin_amdgcn_mfma_f32_16x16x32_bf16(kf1, qf[tt][kk], accS[1][tt], 0, 0, 0);
        }
      }

      const bool diag = (s0 + sblk + 31) > (t0 + tblk);
#pragma unroll
      for (int st = 0; st < 2; ++st)
#pragma unroll
        for (int tt = 0; tt < 2; ++tt) {
          float p[4];
          if (fullmask) {
            p[0] = p[1] = p[2] = p[3] = 0.f;
          } else if (diag) {
            const int sg = s0 + sblk + st * 16 + quad * 4;
            const int tg = t0 + tblk + tt * 16 + l16;
#pragma unroll
            for (int r = 0; r < 4; ++r)
              p[r] = (sg + r <= tg) ? EXP2F(accS[st][tt][r]) : 0.f;
          } else {
#pragma unroll
            for (int r = 0; r < 4; ++r) p[r] = EXP2F(accS[st][tt][r]);
          }
          uint2 pw;   // truncating bf16 pack (bias cancels in normalization)
          pw.x = (__float_as_uint(p[0]) >> 16) | (__float_as_uint(p[1]) & 0xFFFF0000u);
          pw.y = (__float_as_uint(p[2]) >> 16) | (__float_as_uint(p[3]) & 0xFFFF0000u);
          *(uint2*)(sP + (tblk + tt * 16 + l16) * 72 + sblk + st * 16 + quad * 4) = pw;
        }
      __syncthreads();   // P visible to all waves

      // PV: O[t][d] += P * Vt^T ; l[t] += P * 1  (t-block = w_t*32, d-block = w_s*64)
#pragma unroll
      for (int ss = 0; ss < 2; ++ss) {
        bf16x8 pf[2];
#pragma unroll
        for (int tt = 0; tt < 2; ++tt)
          pf[tt] = *(const bf16x8*)(sP + (tblk + tt * 16 + l16) * 72 +
                                    (ss << 5) + (quad << 3));
#pragma unroll
        for (int tt = 0; tt < 2; ++tt)
          lacc[tt] = __builtin_amdgcn_mfma_f32_16x16x32_bf16(pf[tt], onesf, lacc[tt], 0, 0, 0);
#pragma unroll
        for (int dt = 0; dt < 4; ++dt) {
          bf16x8 vf = *(const bf16x8*)(sVt + ((w_s << 6) + dt * 16 + l16) * 64 +
                                       ((((ss << 2) + quad) ^ (l16 & 7)) << 3));
#pragma unroll
          for (int tt = 0; tt < 2; ++tt)
            oacc[tt][dt] = __builtin_amdgcn_mfma_f32_16x16x32_bf16(pf[tt], vf, oacc[tt][dt], 0, 0, 0);
        }
      }
    }

    // epilogue: normalize, transpose O through LDS, coalesced store
    __syncthreads();   // all PV reads of sK/sVt/sP done
#pragma unroll
    for (int tt = 0; tt < 2; ++tt) {
      floatx4 li;
#pragma unroll
      for (int r = 0; r < 4; ++r) li[r] = 1.0f / lacc[tt][r];
#pragma unroll
      for (int dt = 0; dt < 4; ++dt)
#pragma unroll
        for (int r = 0; r < 4; ++r) {
          float v = oacc[tt][dt][r] * li[r];
          sO[(tblk + tt * 16 + quad * 4 + r) * 136 + (w_s << 6) + dt * 16 + l16] =
              (ushort)bf16rne(v);
        }
    }
    __syncthreads();
#pragma unroll
    for (int it = 0; it < 4; ++it) {
      int idx = it * 512 + tid;                  // 0..2047 = 128 rows x 16 chunks
      int rr = idx >> 4, c8 = idx & 15;
      *(uint4*)(y + (bT + t0 + rr) * CDIM + h * HD + c8 * 8) =
          *(const uint4*)(sO + rr * 136 + c8 * 8);
    }
    // top-of-next-half barrier (inside ch loop) protects sO before restaging
  }
}

extern "C" void kernel_launch(void* const* d_in, const int* in_sizes, int n_in,
                              void* d_out, int out_size, void* d_ws, size_t ws_size,
                              hipStream_t stream) {
  const float* x    = (const float*)d_in[0];
  const float* fcos = (const float*)d_in[1];
  const float* fsin = (const float*)d_in[2];
  const float* wq   = (const float*)d_in[3];
  const float* wk   = (const float*)d_in[4];
  const float* wv   = (const float*)d_in[5];
  const float* wo   = (const float*)d_in[6];
  float* out = (float*)d_out;

  // workspace carve (bf16 elems); yb aliases xb (xb dead after gemm1)
  ushort* ws    = (ushort*)d_ws;
  ushort* xb    = ws;                          // 4096*2048 = 8,388,608
  ushort* yb    = ws;                          // alias of xb
  ushort* wqkvb = ws    + 8388608;             // 3072*2048 = 6,291,456
  ushort* wob   = wqkvb + 6291456;             // 2048*2048 = 4,194,304
  ushort* qkv   = wob   + 4194304;             // 4096*3072 = 12,582,912 (v cols unused)
  ushort* vtg   = qkv   + 12582912;            // 2*512*2048 = 2,097,152

  // 1) fp32 -> bf16 casts; wq/wk/wv concatenated row-wise into Wqkv (3072 x 2048)
  cast_f32_bf16x2<<<16384, 256, 0, stream>>>(x,  (uint*)xb,    4194304);
  cast_f32_bf16x2<<< 8192, 256, 0, stream>>>(wq, (uint*)wqkvb, 2097152);
  cast_f32_bf16x2<<< 2048, 256, 0, stream>>>(wk, (uint*)(wqkvb + 4194304), 524288);
  cast_f32_bf16x2<<< 2048, 256, 0, stream>>>(wv, (uint*)(wqkvb + 5242880), 524288);
  cast_f32_bf16x2<<< 8192, 256, 0, stream>>>(wo, (uint*)wob,   2097152);

  // 2) qkv = xb @ Wqkv^T ; V columns (>=2560) written transposed into vtg
  gemm_bt<ushort><<<dim3(QKV_W / 128, MROWS / 128), 256, 0, stream>>>(
      xb, wqkvb, qkv, MROWS, QKV_W, CDIM, 2560, vtg);

  // 3) RoPE in place on q (scaled by QSCALE) and k
  rope_kernel<<<20480, 256, 0, stream>>>(qkv, fcos, fsin);

  // 4) MFMA causal GQA attention -> yb (bf16): Q-tile 128, 8 waves, 256 blocks
  attn_mfma<<<dim3(8, NHEAD, NB), 512, 0, stream>>>(qkv, vtg, yb);

  // 5) out = yb @ wo^T (fp32 out)
  gemm_bt<float><<<dim3(CDIM / 128, MROWS / 128), 256, 0, stream>>>(
      yb, wob, out, MROWS, CDIM, CDIM, 1 << 30, nullptr);
}